// Round 1
// baseline (520.072 us; speedup 1.0000x reference)
//
#include <hip/hip_runtime.h>
#include <cstdint>
#include <cstddef>

#define N_NODES 50000
#define HDIM 64
#define NREL 50
#define NEDGE 800000
#define DCHUNK 196    // ceil(N_NODES/256)
#define CHUNKSH 11    // 2048 dsts per coarse chunk (sort arena granularity)
#define NCHUNK 25     // ceil(50000/2048)
#define NKEY2 (NCHUNK * 2048)   // 51200 fine sort keys: (coarse, sub64, rel)
#define NCH64 782     // ceil(50000/64) fused-processing chunks
#define SCAP 1216     // LDS msg rows per chunk64 (mean 1023, +6 sigma)
#define TDIRN 160     // tile directory cap (max ~126 tiles/chunk)
#define CAP 36864     // arena capacity per coarse chunk
#define TILE 8192     // edges per msplit/place block (1024 thr x 8)

typedef __attribute__((ext_vector_type(8))) short short8;
typedef __attribute__((ext_vector_type(4))) float f32x4;

static __device__ __forceinline__ unsigned short f2bf(float f) {
  union { float f; unsigned int u; } v; v.f = f;
  unsigned int u = v.u;
  unsigned int r = (u + 0x7FFFu + ((u >> 16) & 1u)) >> 16;  // RNE
  return (unsigned short)r;
}

// ---- preprocessing: atomic-light two-level counting sort ------------------

__global__ __launch_bounds__(256) void csort_k(const int* __restrict__ ei,
                                               const int* __restrict__ et,
                                               int* __restrict__ ccur,
                                               int2* __restrict__ ce) {
  __shared__ int chist[32];
  __shared__ int cbase[32];
  int tid = threadIdx.x;
  if (tid < 32) chist[tid] = 0;
  __syncthreads();
  int ebase = blockIdx.x * 1280 + tid;          // 625 blocks x 1280 edges
  int src_[5], dr_[5], ch_[5], loc_[5];
#pragma unroll
  for (int i = 0; i < 5; ++i) {
    int e = ebase + i * 256;
    int src = ei[e];
    int dst = ei[NEDGE + e];
    int r = et[e];
    int ch = dst >> CHUNKSH;
    src_[i] = src;
    dr_[i] = (dst << 6) | r;
    ch_[i] = ch;
    loc_[i] = atomicAdd(&chist[ch], 1);         // LDS
  }
  __syncthreads();
  if (tid < NCHUNK && chist[tid] > 0)
    cbase[tid] = atomicAdd(&ccur[tid], chist[tid]);   // 25 returning/block
  __syncthreads();
#pragma unroll
  for (int i = 0; i < 5; ++i)
    ce[(size_t)ch_[i] * CAP + cbase[ch_[i]] + loc_[i]] = make_int2(src_[i], dr_[i]);
}

// split within coarse chunk: per-dst ranks + per-(sub64,rel) fine-key ranks
__global__ __launch_bounds__(1024) void msplit_k(const int2* __restrict__ ce,
                                                 const int* __restrict__ ccur,
                                                 int* __restrict__ dcur,
                                                 int* __restrict__ kcur,
                                                 int* __restrict__ dkr) {
  __shared__ int dhist[2048], dbase[2048];
  __shared__ int khist[2048], kbase[2048];
  int c = blockIdx.y;
  int len = ccur[c];
  int t0 = blockIdx.x * TILE;
  if (t0 >= len) return;                        // block-uniform
  int tid = threadIdx.x;
  dhist[tid] = 0; dhist[tid + 1024] = 0;
  khist[tid] = 0; khist[tid + 1024] = 0;
  __syncthreads();
  int n = min(TILE, len - t0);
  const int2* seg = ce + (size_t)c * CAP + t0;
  int pk[8], dr_[8];
#pragma unroll
  for (int k = 0; k < 8; ++k) {
    int j = tid + k * 1024;
    if (j < n) {
      int2 v = seg[j];
      dr_[k] = v.y;
      int d11 = (v.y >> 6) & 2047;
      int key11 = (d11 & 0x7C0) | (v.y & 63);   // sub64*64 | rel
      int dl = atomicAdd(&dhist[d11], 1);       // LDS
      int kl = atomicAdd(&khist[key11], 1);     // LDS
      pk[k] = (dl << 16) | kl;
    } else {
      pk[k] = -1;
    }
  }
  __syncthreads();
  int h0 = dhist[tid];
  if (h0 > 0) dbase[tid] = atomicAdd(&dcur[(c << CHUNKSH) + tid], h0);
  int h1 = dhist[tid + 1024];
  if (h1 > 0) dbase[tid + 1024] = atomicAdd(&dcur[(c << CHUNKSH) + tid + 1024], h1);
  int k0 = khist[tid];
  if (k0 > 0) kbase[tid] = atomicAdd(&kcur[(c << CHUNKSH) + tid], k0);
  int k1 = khist[tid + 1024];
  if (k1 > 0) kbase[tid + 1024] = atomicAdd(&kcur[(c << CHUNKSH) + tid + 1024], k1);
  __syncthreads();
#pragma unroll
  for (int k = 0; k < 8; ++k) {
    if (pk[k] >= 0) {
      int d11 = (dr_[k] >> 6) & 2047;
      int key11 = (d11 & 0x7C0) | (dr_[k] & 63);
      int drank = dbase[d11] + (pk[k] >> 16);
      int krank = kbase[key11] + (pk[k] & 0xFFFF);
      dkr[(size_t)c * CAP + t0 + tid + k * 1024] = (drank << 16) | krank;
    }
  }
}

// ---- 51200-key exclusive scan (3 kernels) ---------------------------------

__global__ __launch_bounds__(256) void ksA_k(const int* __restrict__ kcur,
                                             int* __restrict__ kps) {
  __shared__ int red[256];
  int t = threadIdx.x, b = blockIdx.x;
  red[t] = kcur[b * 256 + t];
  __syncthreads();
  for (int s = 128; s > 0; s >>= 1) {
    if (t < s) red[t] += red[t + s];
    __syncthreads();
  }
  if (t == 0) kps[b] = red[0];
}

__global__ __launch_bounds__(256) void ksB_k(const int* __restrict__ kps,
                                             int* __restrict__ kpsb) {
  __shared__ int a[256], bb[256];
  int t = threadIdx.x;
  int v = (t < 200) ? kps[t] : 0;
  a[t] = v;
  __syncthreads();
  bool flip = false;
  for (int off = 1; off < 256; off <<= 1) {
    int* c = flip ? bb : a;
    int* n = flip ? a : bb;
    int x = c[t];
    if (t >= off) x += c[t - off];
    n[t] = x;
    __syncthreads();
    flip = !flip;
  }
  int incl = (flip ? bb : a)[t];
  kpsb[t] = incl - v;
}

__global__ __launch_bounds__(256) void ksC_k(const int* __restrict__ kcur,
                                             const int* __restrict__ kpsb,
                                             int* __restrict__ key_off) {
  __shared__ int a[256], bb[256];
  int t = threadIdx.x, b = blockIdx.x;
  int v = kcur[b * 256 + t];
  a[t] = v;
  __syncthreads();
  bool flip = false;
  for (int off = 1; off < 256; off <<= 1) {
    int* c = flip ? bb : a;
    int* n = flip ? a : bb;
    int x = c[t];
    if (t >= off) x += c[t - off];
    n[t] = x;
    __syncthreads();
    flip = !flip;
  }
  int incl = (flip ? bb : a)[t];
  key_off[b * 256 + t] = kpsb[b] + (incl - v);
}

// ---- dst_off scan (unchanged) ---------------------------------------------

__global__ __launch_bounds__(256) void dsA_k(const int* __restrict__ dcnt,
                                             int* __restrict__ psum) {
  __shared__ int red[256];
  int t = threadIdx.x, b = blockIdx.x;
  int idx = b * DCHUNK + t;
  int v = (t < DCHUNK && idx < N_NODES) ? dcnt[idx] : 0;
  red[t] = v;
  __syncthreads();
  for (int s = 128; s > 0; s >>= 1) {
    if (t < s) red[t] += red[t + s];
    __syncthreads();
  }
  if (t == 0) psum[b] = red[0];
}

__global__ __launch_bounds__(256) void dsB_k(const int* __restrict__ psum,
                                             int* __restrict__ psb,
                                             int* __restrict__ dst_off) {
  __shared__ int a[256], bb[256];
  int t = threadIdx.x;
  int v = psum[t];
  a[t] = v;
  __syncthreads();
  bool flip = false;
  for (int off = 1; off < 256; off <<= 1) {
    int* c = flip ? bb : a;
    int* n = flip ? a : bb;
    int x = c[t];
    if (t >= off) x += c[t - off];
    n[t] = x;
    __syncthreads();
    flip = !flip;
  }
  int incl = (flip ? bb : a)[t];
  psb[t] = incl - v;
  if (t == 255) dst_off[N_NODES] = incl;
}

__global__ __launch_bounds__(256) void dsC_k(const int* __restrict__ dcnt,
                                             const int* __restrict__ psb,
                                             int* __restrict__ dst_off) {
  __shared__ int a[256], bb[256];
  int t = threadIdx.x, b = blockIdx.x;
  int idx = b * DCHUNK + t;
  int v = (t < DCHUNK && idx < N_NODES) ? dcnt[idx] : 0;
  a[t] = v;
  __syncthreads();
  bool flip = false;
  for (int off = 1; off < 256; off <<= 1) {
    int* c = flip ? bb : a;
    int* n = flip ? a : bb;
    int x = c[t];
    if (t >= off) x += c[t - off];
    n[t] = x;
    __syncthreads();
    flip = !flip;
  }
  int incl = (flip ? bb : a)[t];
  if (t < DCHUNK && idx < N_NODES) dst_off[idx] = psb[b] + (incl - v);
}

// place: es in (chunk64, rel) global order; rpr stores CHUNK-LOCAL positions
__global__ __launch_bounds__(1024) void place_k(const int2* __restrict__ ce,
                                                const int* __restrict__ ccur,
                                                const int* __restrict__ dkr,
                                                const int* __restrict__ key_off,
                                                const int* __restrict__ dst_off,
                                                int* __restrict__ es,
                                                int* __restrict__ rpr) {
  int c = blockIdx.y;
  int len = ccur[c];
  int t0 = blockIdx.x * TILE;
  if (t0 >= len) return;
  int tid = threadIdx.x;
  int n = min(TILE, len - t0);
  size_t base = (size_t)c * CAP + t0;
#pragma unroll
  for (int k = 0; k < 8; ++k) {
    int j = tid + k * 1024;
    if (j < n) {
      int2 v = ce[base + j];
      int dk = dkr[base + j];
      int dst = v.y >> 6;
      int rel = v.y & 63;
      int d11 = dst & 2047;
      int gkey = (c << CHUNKSH) | (d11 & 0x7C0) | rel;
      int pos = key_off[gkey] + (dk & 0xFFFF);
      int cb = key_off[(c << CHUNKSH) | (d11 & 0x7C0)];   // chunk64 start
      int local = (pos - cb) & 2047;
      int dp = dst_off[dst] + (dk >> 16);
      es[pos] = v.x;
      rpr[dp] = (local << 6) | rel;
    }
  }
}

// coefd[j] = 1 / #(edges in j's dst-segment with same rel); rel = rpr&63
__global__ __launch_bounds__(256) void coef_k(const int* __restrict__ rpr,
                                              const int* __restrict__ dst_off,
                                              float* __restrict__ coefd) {
  int lane = threadIdx.x & 63;
  int wv = (blockIdx.x * 256 + threadIdx.x) >> 6;
  int half = lane >> 5, l = lane & 31;
  int dst = wv * 2 + half;
  if (dst >= N_NODES) return;
  int lo = dst_off[dst], hi = dst_off[dst + 1];
  for (int j = lo + l; j < hi; j += 32) {
    int r = rpr[j] & 63;
    int c = 0;
    for (int k = lo; k < hi; ++k) c += ((rpr[k] & 63) == r);
    coefd[j] = 1.0f / (float)c;
  }
}

// weight prep: transpose to [r][o][d] bf16; expand block-diagonal to dense
__global__ void prep_k(const float* __restrict__ w0, const float* __restrict__ w1,
                       const float* __restrict__ w2,
                       const float* __restrict__ wr0f, const float* __restrict__ wr1f,
                       const float* __restrict__ wr2f,
                       unsigned short* __restrict__ Wt0, unsigned short* __restrict__ Wt1,
                       unsigned short* __restrict__ Wt2,
                       unsigned short* __restrict__ Wr0, unsigned short* __restrict__ Wr1,
                       unsigned short* __restrict__ Wr2) {
  int idx = blockIdx.x * 256 + threadIdx.x;
  if (idx < NREL * 4096) {
    int r = idx >> 12, rem = idx & 4095, d = rem >> 6, o = rem & 63;
    int tpos = (r << 12) + (o << 6) + d;        // [r][o][d]
    Wt2[tpos] = f2bf(w2[idx]);                  // w2 is [r][d][o]
    int b = o >> 4;
    float v0 = 0.f, v1 = 0.f;
    if (b == (d >> 4)) {
      int widx = ((r * 4 + b) * 16 + (d & 15)) * 16 + (o & 15);
      v0 = w0[widx];
      v1 = w1[widx];
    }
    Wt0[tpos] = f2bf(v0);
    Wt1[tpos] = f2bf(v1);
  }
  if (idx < 4096) {
    int d = idx >> 6, o = idx & 63;
    int tpos = (o << 6) + d;
    Wr0[tpos] = f2bf(wr0f[idx]);
    Wr1[tpos] = f2bf(wr1f[idx]);
    Wr2[tpos] = f2bf(wr2f[idx]);
  }
}

// fp32 -> bf16 convert (layer-0 input only)
__global__ void conv_k(const float* __restrict__ in, unsigned short* __restrict__ out) {
  int i = blockIdx.x * 256 + threadIdx.x;
  out[i] = f2bf(in[i]);
}

// h[n,:] = bias + x[n,:] @ w_root
__global__ __launch_bounds__(256) void root_k(const unsigned short* __restrict__ xbf,
                                              const unsigned short* __restrict__ wr,
                                              const float* __restrict__ bias,
                                              float* __restrict__ out) {
  int wid = threadIdx.x >> 6, lane = threadIdx.x & 63;
  int n15 = lane & 15, quad = lane >> 4;
  int t = blockIdx.x * 4 + wid;
  if (t >= N_NODES / 16) return;
  short8 bfr[4][2];
#pragma unroll
  for (int nb = 0; nb < 4; ++nb)
#pragma unroll
    for (int k = 0; k < 2; ++k)
      bfr[nb][k] = *reinterpret_cast<const short8*>(wr + ((nb * 16 + n15) << 6) + k * 32 + quad * 8);
  float bv[4];
#pragma unroll
  for (int nb = 0; nb < 4; ++nb) bv[nb] = bias[nb * 16 + n15];

  int base = t * 16;
  const short8* xr = reinterpret_cast<const short8*>(xbf + (size_t)(base + n15) * 64);
  short8 a0 = xr[quad], a1 = xr[4 + quad];
  f32x4 acc[4];
#pragma unroll
  for (int nb = 0; nb < 4; ++nb) acc[nb] = (f32x4){0.f, 0.f, 0.f, 0.f};
#pragma unroll
  for (int nb = 0; nb < 4; ++nb) {
    acc[nb] = __builtin_amdgcn_mfma_f32_16x16x32_bf16(a0, bfr[nb][0], acc[nb], 0, 0, 0);
    acc[nb] = __builtin_amdgcn_mfma_f32_16x16x32_bf16(a1, bfr[nb][1], acc[nb], 0, 0, 0);
  }
#pragma unroll
  for (int i = 0; i < 4; ++i) {
    int node = base + quad * 4 + i;
#pragma unroll
    for (int nb = 0; nb < 4; ++nb)
      out[(size_t)node * 64 + nb * 16 + n15] = acc[nb][i] + bv[nb];
  }
}

// ---- fused per-chunk64 edge-GEMM (into LDS) + aggregation ------------------
// Phase 1: per-rel MFMA tiles of this chunk's edges -> smsg (LDS, never HBM).
// Phase 2: per-dst sum of coef*smsg rows + h, ReLU/bf16 or fp32 out.
__global__ __launch_bounds__(1024) void fused_k(const unsigned short* __restrict__ xbf,
                                                const unsigned short* __restrict__ wt,
                                                const int* __restrict__ es,
                                                const int* __restrict__ key_off,
                                                const float* __restrict__ h,
                                                const float* __restrict__ coefd,
                                                const int* __restrict__ rpr,
                                                const int* __restrict__ dst_off,
                                                float* __restrict__ outf,
                                                unsigned short* __restrict__ outbf,
                                                int mode) {
  __shared__ unsigned short smsg[SCAP * 64];    // 152 KB
  __shared__ int tdir[TDIRN];
  __shared__ int s_ntiles;
  int c = blockIdx.x;                           // chunk64 id
  int g = c << 6;                               // first gkey of this chunk
  int tid = threadIdx.x;
  int wid = tid >> 6, lane = tid & 63;
  int n15 = lane & 15, quad = lane >> 4;
  int ebase = key_off[g];                       // global edge base of chunk

  // wave 0 builds the tile directory: (rowstart, rowend, rel) per MFMA tile
  if (wid == 0) {
    int r = lane;
    int len = (r < NREL) ? key_off[g + r + 1] - key_off[g + r] : 0;
    int ntl = (len + 15) >> 4;
    int srow = len, stile = ntl;
    for (int off = 1; off < 64; off <<= 1) {
      int pr = __shfl_up(srow, off);
      int pt = __shfl_up(stile, off);
      if (lane >= off) { srow += pr; stile += pt; }
    }
    int rowstart = srow - len;                  // exclusive prefix
    int tstart = stile - ntl;
    for (int t = 0; t < ntl; ++t) {
      int rs = rowstart + t * 16;
      int re = min(rowstart + len, rs + 16);
      int di = tstart + t;
      if (di < TDIRN)
        tdir[di] = ((rs & 2047) << 17) | ((re & 2047) << 6) | r;
    }
    if (lane == 63) s_ntiles = min(stile, TDIRN);
  }
  __syncthreads();

  // phase 1: contiguous tile ranges per wave (weight reuse across same-rel runs)
  int nt = s_ntiles;
  int T = (nt + 15) >> 4;
  int t1 = min(nt, (wid + 1) * T);
  int prevrel = -1;
  short8 bfr[4][2];
  for (int ti = wid * T; ti < t1; ++ti) {
    int pk = tdir[ti];
    int rel = pk & 63;
    int rs = (pk >> 17) & 2047;
    int re = (pk >> 6) & 2047;
    if (rel != prevrel) {
      const unsigned short* wr = wt + ((size_t)rel << 12);
#pragma unroll
      for (int nb = 0; nb < 4; ++nb)
#pragma unroll
        for (int k = 0; k < 2; ++k)
          bfr[nb][k] = *reinterpret_cast<const short8*>(wr + ((nb * 16 + n15) << 6) + k * 32 + quad * 8);
      prevrel = rel;
    }
    int row = rs + n15;
    if (row > re - 1) row = re - 1;             // clamp within segment (same rel)
    int src = es[ebase + row];
    const short8* xr = reinterpret_cast<const short8*>(xbf + (size_t)src * 64);
    short8 a0 = xr[quad], a1 = xr[4 + quad];
    f32x4 acc[4];
#pragma unroll
    for (int nb = 0; nb < 4; ++nb) acc[nb] = (f32x4){0.f, 0.f, 0.f, 0.f};
#pragma unroll
    for (int nb = 0; nb < 4; ++nb) {
      acc[nb] = __builtin_amdgcn_mfma_f32_16x16x32_bf16(a0, bfr[nb][0], acc[nb], 0, 0, 0);
      acc[nb] = __builtin_amdgcn_mfma_f32_16x16x32_bf16(a1, bfr[nb][1], acc[nb], 0, 0, 0);
    }
#pragma unroll
    for (int i = 0; i < 4; ++i) {
      int r2 = rs + quad * 4 + i;
      if (r2 < re && r2 < SCAP) {
#pragma unroll
        for (int nb = 0; nb < 4; ++nb)
          smsg[r2 * 64 + nb * 16 + n15] = f2bf(acc[nb][i]);
      }
    }
  }
  __syncthreads();

  // phase 2: half-wave per dst, lane l handles elements 2l, 2l+1
  const unsigned int* m32 = reinterpret_cast<const unsigned int*>(smsg);
  int half = lane >> 5, l = lane & 31;
#pragma unroll
  for (int it = 0; it < 2; ++it) {
    int dl_ = it * 32 + wid * 2 + half;         // 0..63
    int dst = (c << 6) + dl_;
    if (dst < N_NODES) {
      int lo = dst_off[dst], hi = dst_off[dst + 1];
      float ax = h[(size_t)dst * 64 + 2 * l];
      float ay = h[(size_t)dst * 64 + 2 * l + 1];
      for (int j = lo; j < hi; ++j) {
        int rp = rpr[j];
        int lp = (rp >> 6) & 2047;
        if (lp >= SCAP) lp = SCAP - 1;          // overflow-safe (never in practice)
        float cf = coefd[j];
        unsigned int u = m32[lp * 32 + l];
        union { unsigned int u; float f; } cx, cy;
        cx.u = (u & 0xFFFFu) << 16;
        cy.u = u & 0xFFFF0000u;
        ax += cf * cx.f;
        ay += cf * cy.f;
      }
      if (mode == 0) {
        float fx = fmaxf(ax, 0.f), fy = fmaxf(ay, 0.f);
        unsigned int pkv = ((unsigned int)f2bf(fy) << 16) | (unsigned int)f2bf(fx);
        *reinterpret_cast<unsigned int*>(outbf + (size_t)dst * 64 + 2 * l) = pkv;
      } else {
        float2 o2; o2.x = ax; o2.y = ay;
        *reinterpret_cast<float2*>(outf + (size_t)dst * 64 + 2 * l) = o2;
      }
    }
  }
}

// ---- launcher ------------------------------------------------------------

extern "C" void kernel_launch(void* const* d_in, const int* in_sizes, int n_in,
                              void* d_out, int out_size, void* d_ws, size_t ws_size,
                              hipStream_t stream) {
  const float* x   = (const float*)d_in[0];
  const int*   ei  = (const int*)d_in[1];
  const int*   et  = (const int*)d_in[2];
  const float* w0  = (const float*)d_in[3];
  const float* wr0 = (const float*)d_in[4];
  const float* b0  = (const float*)d_in[5];
  const float* w1  = (const float*)d_in[6];
  const float* wr1 = (const float*)d_in[7];
  const float* b1  = (const float*)d_in[8];
  const float* w2  = (const float*)d_in[9];
  const float* wr2 = (const float*)d_in[10];
  const float* b2  = (const float*)d_in[11];
  float* out = (float*)d_out;

  char* p = (char*)d_ws;
  auto take = [&](size_t bytes) -> char* {
    char* q = p;
    p += (bytes + 255) & ~(size_t)255;
    return q;
  };
  // ccur + dcur + kcur adjacent so one memset clears all three.
  char*  zbase   = p;
  int*   ccur    = (int*)take(32 * 4);
  int*   dcur    = (int*)take((size_t)NCHUNK * 2048 * 4);
  int*   kcur    = (int*)take((size_t)NKEY2 * 4);           // 51200 fine keys
  size_t zbytes  = (size_t)(p - zbase);
  int*   key_off = (int*)take((size_t)(NKEY2 + 1) * 4);
  int*   dst_off = (int*)take((size_t)(N_NODES + 1) * 4);
  int*   psum    = (int*)take(256 * 4);
  int*   psb     = (int*)take(256 * 4);
  int*   kps     = (int*)take(256 * 4);
  int*   kpsb    = (int*)take(256 * 4);
  int2*  ce      = (int2*)take((size_t)NCHUNK * CAP * 8);   // 7.4 MB arenas
  int*   dkr     = (int*)take((size_t)NCHUNK * CAP * 4);    // 3.7 MB
  int*   es      = (int*)take((size_t)NEDGE * 4);
  int*   rpr     = (int*)take((size_t)NEDGE * 4);
  float* coefd   = (float*)take((size_t)NEDGE * 4);
  unsigned short* xb0 = (unsigned short*)take((size_t)N_NODES * 64 * 2);
  unsigned short* xb1 = (unsigned short*)take((size_t)N_NODES * 64 * 2);
  float* h       = (float*)take((size_t)N_NODES * 64 * 4);
  unsigned short* Wt0 = (unsigned short*)take((size_t)NREL * 4096 * 2);
  unsigned short* Wt1 = (unsigned short*)take((size_t)NREL * 4096 * 2);
  unsigned short* Wt2 = (unsigned short*)take((size_t)NREL * 4096 * 2);
  unsigned short* Wr0 = (unsigned short*)take(4096 * 2);
  unsigned short* Wr1 = (unsigned short*)take(4096 * 2);
  unsigned short* Wr2 = (unsigned short*)take(4096 * 2);

  // preprocessing (edge structure shared by all 3 layers)
  hipMemsetAsync(zbase, 0, zbytes, stream);        // ccur + dcur + kcur
  csort_k<<<NEDGE / 1280, 256, 0, stream>>>(ei, et, ccur, ce);
  dim3 mg(5, NCHUNK);                              // 5 tiles x 8192 covers CAP
  msplit_k<<<mg, 1024, 0, stream>>>(ce, ccur, dcur, kcur, dkr);
  ksA_k<<<NKEY2 / 256, 256, 0, stream>>>(kcur, kps);
  ksB_k<<<1, 256, 0, stream>>>(kps, kpsb);
  ksC_k<<<NKEY2 / 256, 256, 0, stream>>>(kcur, kpsb, key_off);
  dsA_k<<<256, 256, 0, stream>>>(dcur, psum);
  dsB_k<<<1, 256, 0, stream>>>(psum, psb, dst_off);
  dsC_k<<<256, 256, 0, stream>>>(dcur, psb, dst_off);
  place_k<<<mg, 1024, 0, stream>>>(ce, ccur, dkr, key_off, dst_off, es, rpr);
  coef_k<<<N_NODES / 8, 256, 0, stream>>>(rpr, dst_off, coefd);
  prep_k<<<(NREL * 4096 + 255) / 256, 256, 0, stream>>>(w0, w1, w2, wr0, wr1, wr2,
                                                        Wt0, Wt1, Wt2, Wr0, Wr1, Wr2);

  const int conv_blocks = N_NODES * 64 / 256;      // 12500, exact
  const int root_blocks = (N_NODES / 16 + 3) / 4;  // 782

  // layer 0  (x double-buffered: fused reads xb_in while writing xb_out)
  conv_k<<<conv_blocks, 256, 0, stream>>>(x, xb0);
  root_k<<<root_blocks, 256, 0, stream>>>(xb0, Wr0, b0, h);
  fused_k<<<NCH64, 1024, 0, stream>>>(xb0, Wt0, es, key_off, h, coefd, rpr, dst_off,
                                      nullptr, xb1, 0);
  // layer 1
  root_k<<<root_blocks, 256, 0, stream>>>(xb1, Wr1, b1, h);
  fused_k<<<NCH64, 1024, 0, stream>>>(xb1, Wt1, es, key_off, h, coefd, rpr, dst_off,
                                      nullptr, xb0, 0);
  // layer 2 (no ReLU, fp32 out)
  root_k<<<root_blocks, 256, 0, stream>>>(xb0, Wr2, b2, h);
  fused_k<<<NCH64, 1024, 0, stream>>>(xb0, Wt2, es, key_off, h, coefd, rpr, dst_off,
                                      out, nullptr, 1);
}